// Round 11
// baseline (95.262 us; speedup 1.0000x reference)
//
#include <hip/hip_runtime.h>

// RNN scan: h_{t+1} = relu(W_hh @ h_t + x_t * w_x), out = W_hy @ h_T
// B=8192, T=512, H=64.
// Round 11 = round 10 (16x16x32 bf16, 4-wave M-split, 16 cols/block,
// grid 512 = 2 blocks/CU) + conflict-free LDS reads.
//   r10 profile: SQ_LDS_BANK_CONFLICT 1.26e7 = +6 cyc on each of 2.1M
//   ds_read_b128 (start bank 4(c+g)%32: only 8 start positions, 4 lanes
//   each -> banks 8-deep vs 4 minimum). LDS pipe ~77% busy => bottleneck.
//   Fix: read b64 granule (start = 4(c+g)+2h: 16 positions, 2 lanes/start,
//   2 dwords/lane -> 2/bank = m136-free). 4x ds_read_b64, anti-merge
//   memory clobbers between them; C++ loads keep compiler lgkm waits.
// Layouts: C (m89): col=lane&15, row=4*(lane>>4)+reg.
//   A/B (r10-verified): row/col=lane&15, k=8*(lane>>4)+e.
// Exchange: chunk(c,G) = rows [8G,8G+8) of col c; col stride 9 chunks.
// Double-buffered hbuf + single {lgkmcnt(0); s_barrier} per step.

typedef __bf16 bf16x8 __attribute__((ext_vector_type(8)));
typedef float f32x4 __attribute__((ext_vector_type(4)));
typedef unsigned int u32x4 __attribute__((ext_vector_type(4)));
typedef unsigned int u32x2 __attribute__((ext_vector_type(2)));

#define RNN_B 8192
#define RNN_T 512
#define RNN_H 64

__global__ __launch_bounds__(256, 1) void rnn_scan_kernel(
    const float* __restrict__ x,
    const float* __restrict__ Wxh,
    const float* __restrict__ Whh,
    const float* __restrict__ Why,
    float* __restrict__ out)
{
  const int tid  = threadIdx.x;
  const int mu   = tid >> 6;       // wave: owns h rows [16mu, 16mu+16)
  const int lane = tid & 63;
  const int c    = lane & 15;      // batch col within block
  const int g    = lane >> 4;      // lane group (C rows 4g..4g+3, B k 8g..8g+7)
  const int b0   = blockIdx.x * 16;

  // [buf][col][chunk G (pad 8->9)]; chunk = rows [8G,8G+8) of col c, bf16
  __shared__ u32x4 hbuf[2][16][9];           // 4608 B
  __shared__ float partial[4][16];

  // ---- A frags: W_hh[16mu + c][32k + 8g + e], k-halves k=0,1 ----
  bf16x8 A[2];
#pragma unroll
  for (int k = 0; k < 2; ++k) {
    const float* wp = Whh + (size_t)(16 * mu + c) * RNN_H + 32 * k + 8 * g;
    float4 w0 = *(const float4*)(wp);
    float4 w1 = *(const float4*)(wp + 4);
    bf16x8 f;
    f[0] = (__bf16)w0.x; f[1] = (__bf16)w0.y; f[2] = (__bf16)w0.z; f[3] = (__bf16)w0.w;
    f[4] = (__bf16)w1.x; f[5] = (__bf16)w1.y; f[6] = (__bf16)w1.z; f[7] = (__bf16)w1.w;
    A[k] = f;
  }

  // ---- w_x per C slot: row = 16mu + 4g + r ----
  f32x4 wxv;
#pragma unroll
  for (int r = 0; r < 4; ++r) wxv[r] = Wxh[16 * mu + 4 * g + r];

  const float* xrow = x + (size_t)(b0 + c) * RNN_T;
  float4 xc0 = *(const float4*)(xrow);
  float4 xc1 = *(const float4*)(xrow + 4);

  f32x4 acc = {};                  // own rows' pre-relu h (4 regs)
  u32x4 Bv0 = {}, Bv1 = {};        // B frags, k-halves (h_0 = 0)
  unsigned zero_u = 0;

  for (int tb = 0; tb < RNN_T; tb += 8) {
    const int tn = (tb + 8 < RNN_T) ? tb + 8 : tb;
    float4 xn0 = *(const float4*)(xrow + tn);
    float4 xn1 = *(const float4*)(xrow + tn + 4);
    const float xs[8] = {xc0.x, xc0.y, xc0.z, xc0.w, xc1.x, xc1.y, xc1.z, xc1.w};
#pragma unroll
    for (int j = 0; j < 8; ++j) {
      const float xv = xs[j];
      // h update: 2 chained 16x16x32 MFMAs, C-in = f32-exact x-term
      f32x4 a = wxv * xv;
      a = __builtin_amdgcn_mfma_f32_16x16x32_bf16(A[0], __builtin_bit_cast(bf16x8, Bv0), a, 0, 0, 0);
      a = __builtin_amdgcn_mfma_f32_16x16x32_bf16(A[1], __builtin_bit_cast(bf16x8, Bv1), a, 0, 0, 0);
      acc = a;

      // pack own 4 rows (16mu+4g+0..3, col c): cvt_pk (RNE) + relu on packed
      unsigned w0, w1;
      asm("v_cvt_pk_bf16_f32 %0, %1, %2" : "=v"(w0) : "v"(a[0]), "v"(a[1]));
      asm("v_cvt_pk_bf16_f32 %0, %1, %2" : "=v"(w1) : "v"(a[2]), "v"(a[3]));
      asm("v_pk_max_i16 %0, %1, %2" : "=v"(w0) : "v"(w0), "v"(zero_u));
      asm("v_pk_max_i16 %0, %1, %2" : "=v"(w1) : "v"(w1), "v"(zero_u));

      // write into chunk G = 2mu + (g>>1), half (g&1)  [rows 16mu+4g..+3]
      const int q = (j + 1) & 1;               // parity of t+1 (tb even)
      u32x2 wpair = {w0, w1};
      *(u32x2*)((char*)&hbuf[q][c][2 * mu + (g >> 1)] + 8 * (g & 1)) = wpair;
      asm volatile("s_waitcnt lgkmcnt(0)\n\ts_barrier" ::: "memory");

      // read B frags for next step as 4x ds_read_b64 (conflict-free starts
      // 4(c+g)+2h); clobbers stop the load-combiner re-merging to b128
      const unsigned* cb = (const unsigned*)&hbuf[q][c][0];
      u32x2 ra0 = *(const u32x2*)(cb + 4 * g);          // chunk g, dwords 0-1
      asm volatile("" ::: "memory");
      u32x2 ra1 = *(const u32x2*)(cb + 4 * g + 2);      // chunk g, dwords 2-3
      asm volatile("" ::: "memory");
      u32x2 rb0 = *(const u32x2*)(cb + 16 + 4 * g);     // chunk 4+g, dwords 0-1
      asm volatile("" ::: "memory");
      u32x2 rb1 = *(const u32x2*)(cb + 16 + 4 * g + 2); // chunk 4+g, dwords 2-3
      Bv0[0] = ra0[0]; Bv0[1] = ra0[1]; Bv0[2] = ra1[0]; Bv0[3] = ra1[1];
      Bv1[0] = rb0[0]; Bv1[1] = rb0[1]; Bv1[2] = rb1[0]; Bv1[3] = rb1[1];
    }
    xc0 = xn0; xc1 = xn1;
  }

  // ---- epilogue: out[b] = sum_rows Why * relu(h_T) ----
  float pw = 0.0f;
#pragma unroll
  for (int r = 0; r < 4; ++r)
    pw += Why[16 * mu + 4 * g + r] * fmaxf(acc[r], 0.0f);
  pw += __shfl_xor(pw, 16, 64);
  pw += __shfl_xor(pw, 32, 64);
  if (lane < 16) partial[mu][c] = pw;
  __syncthreads();
  if (mu == 0 && lane < 16)
    out[b0 + c] = partial[0][c] + partial[1][c] + partial[2][c] + partial[3][c];
}

extern "C" void kernel_launch(void* const* d_in, const int* in_sizes, int n_in,
                              void* d_out, int out_size, void* d_ws, size_t ws_size,
                              hipStream_t stream) {
  const float* x   = (const float*)d_in[0];
  const float* Wxh = (const float*)d_in[1];
  const float* Whh = (const float*)d_in[2];
  const float* Why = (const float*)d_in[3];
  float* out = (float*)d_out;
  (void)in_sizes; (void)n_in; (void)out_size; (void)d_ws; (void)ws_size;
  rnn_scan_kernel<<<dim3(RNN_B / 16), dim3(256), 0, stream>>>(x, Wxh, Whh, Why, out);
}

// Round 12
// 88.174 us; speedup vs baseline: 1.0804x; 1.0804x over previous
//
#include <hip/hip_runtime.h>

// RNN scan: h_{t+1} = relu(W_hh @ h_t + x_t * w_x), out = W_hy @ h_T
// B=8192, T=512, H=64.
// Round 12 = round 10 (16x16x32 bf16, 4-wave M-split, 16 cols/block,
// grid 512 = 2 blocks/CU) with a LANE-MAJOR exchange buffer:
//   r10/r11 conflicts (1.26e7, +6cyc per b128 read) came from chunk-column
//   reads with 8 start-slots x 4 lanes (4-way dword-subphase conflict).
//   Fix: reader lane l's full B-frag lives at byte 16*l (flat stride-1
//   b128 = r5-r8's measured-zero-conflict pattern). Writers scatter:
//   wave mu lane (c',g') -> kh = mu>>1, reader l = c'+32(mu&1)+16(g'>>1),
//   dword pair 2(g'&1) -- write banks 4c'+2(g'&1): 16 slots, 2-way = free.
// Layouts: C (m89): col=lane&15, row=4*(lane>>4)+reg.
//   A/B (r10-verified): row/col=lane&15, k=8*(lane>>4)+e.
// Double-buffered + single {lgkmcnt(0); s_barrier} per step (WAR-safe as
// r8/r10: reads of buf q are lgkm-drained before that wave's next barrier).

typedef __bf16 bf16x8 __attribute__((ext_vector_type(8)));
typedef float f32x4 __attribute__((ext_vector_type(4)));
typedef unsigned int u32x4 __attribute__((ext_vector_type(4)));
typedef unsigned int u32x2 __attribute__((ext_vector_type(2)));

#define RNN_B 8192
#define RNN_T 512
#define RNN_H 64

__global__ __launch_bounds__(256, 1) void rnn_scan_kernel(
    const float* __restrict__ x,
    const float* __restrict__ Wxh,
    const float* __restrict__ Whh,
    const float* __restrict__ Why,
    float* __restrict__ out)
{
  const int tid  = threadIdx.x;
  const int mu   = tid >> 6;       // wave: owns h rows [16mu, 16mu+16)
  const int lane = tid & 63;
  const int c    = lane & 15;      // batch col within block
  const int g    = lane >> 4;      // lane group (C rows 4g..4g+3, B k 8g..8g+7)
  const int b0   = blockIdx.x * 16;

  // [buf][khalf][reader lane]: reader lane l reads its 16B frag at 16*l
  __shared__ u32x4 xbuf[2][2][256];          // 16 KiB
  __shared__ float partial[4][16];

  // ---- A frags: W_hh[16mu + c][32k + 8g + e], k-halves k=0,1 ----
  bf16x8 A[2];
#pragma unroll
  for (int k = 0; k < 2; ++k) {
    const float* wp = Whh + (size_t)(16 * mu + c) * RNN_H + 32 * k + 8 * g;
    float4 w0 = *(const float4*)(wp);
    float4 w1 = *(const float4*)(wp + 4);
    bf16x8 f;
    f[0] = (__bf16)w0.x; f[1] = (__bf16)w0.y; f[2] = (__bf16)w0.z; f[3] = (__bf16)w0.w;
    f[4] = (__bf16)w1.x; f[5] = (__bf16)w1.y; f[6] = (__bf16)w1.z; f[7] = (__bf16)w1.w;
    A[k] = f;
  }

  // ---- w_x per C slot: row = 16mu + 4g + r ----
  f32x4 wxv;
#pragma unroll
  for (int r = 0; r < 4; ++r) wxv[r] = Wxh[16 * mu + 4 * g + r];

  // writer target: kh = mu>>1, reader lane rl, dword-pair offset 8*(g&1)
  const int kh = mu >> 1;
  const int rl = c + 32 * (mu & 1) + 16 * (g >> 1);

  const float* xrow = x + (size_t)(b0 + c) * RNN_T;
  float4 xc0 = *(const float4*)(xrow);
  float4 xc1 = *(const float4*)(xrow + 4);

  f32x4 acc = {};                  // own rows' pre-relu h (4 regs)
  u32x4 Bv0 = {}, Bv1 = {};        // B frags, k-halves (h_0 = 0)
  unsigned zero_u = 0;

  for (int tb = 0; tb < RNN_T; tb += 8) {
    const int tn = (tb + 8 < RNN_T) ? tb + 8 : tb;
    float4 xn0 = *(const float4*)(xrow + tn);
    float4 xn1 = *(const float4*)(xrow + tn + 4);
    const float xs[8] = {xc0.x, xc0.y, xc0.z, xc0.w, xc1.x, xc1.y, xc1.z, xc1.w};
#pragma unroll
    for (int j = 0; j < 8; ++j) {
      const float xv = xs[j];
      // h update: 2 chained 16x16x32 MFMAs, C-in = f32-exact x-term
      f32x4 a = wxv * xv;
      a = __builtin_amdgcn_mfma_f32_16x16x32_bf16(A[0], __builtin_bit_cast(bf16x8, Bv0), a, 0, 0, 0);
      a = __builtin_amdgcn_mfma_f32_16x16x32_bf16(A[1], __builtin_bit_cast(bf16x8, Bv1), a, 0, 0, 0);
      acc = a;

      // pack own 4 rows (16mu+4g+0..3, col c): cvt_pk (RNE) + relu on packed
      unsigned w0, w1;
      asm("v_cvt_pk_bf16_f32 %0, %1, %2" : "=v"(w0) : "v"(a[0]), "v"(a[1]));
      asm("v_cvt_pk_bf16_f32 %0, %1, %2" : "=v"(w1) : "v"(a[2]), "v"(a[3]));
      asm("v_pk_max_i16 %0, %1, %2" : "=v"(w0) : "v"(w0), "v"(zero_u));
      asm("v_pk_max_i16 %0, %1, %2" : "=v"(w1) : "v"(w1), "v"(zero_u));

      // scatter-write into reader lane rl's frag word (dwords 2(g&1)..+1)
      const int q = (j + 1) & 1;               // parity of t+1 (tb even)
      u32x2 wpair = {w0, w1};
      *(u32x2*)((char*)&xbuf[q][kh][rl] + 8 * (g & 1)) = wpair;
      asm volatile("s_waitcnt lgkmcnt(0)\n\ts_barrier" ::: "memory");
      // flat lane-major reads: byte 16*lane -> conflict-free b128
      Bv0 = xbuf[q][0][lane];
      Bv1 = xbuf[q][1][lane];
    }
    xc0 = xn0; xc1 = xn1;
  }

  // ---- epilogue: out[b] = sum_rows Why * relu(h_T) ----
  float pw = 0.0f;
#pragma unroll
  for (int r = 0; r < 4; ++r)
    pw += Why[16 * mu + 4 * g + r] * fmaxf(acc[r], 0.0f);
  pw += __shfl_xor(pw, 16, 64);
  pw += __shfl_xor(pw, 32, 64);
  if (lane < 16) partial[mu][c] = pw;
  __syncthreads();
  if (mu == 0 && lane < 16)
    out[b0 + c] = partial[0][c] + partial[1][c] + partial[2][c] + partial[3][c];
}

extern "C" void kernel_launch(void* const* d_in, const int* in_sizes, int n_in,
                              void* d_out, int out_size, void* d_ws, size_t ws_size,
                              hipStream_t stream) {
  const float* x   = (const float*)d_in[0];
  const float* Wxh = (const float*)d_in[1];
  const float* Whh = (const float*)d_in[2];
  const float* Why = (const float*)d_in[3];
  float* out = (float*)d_out;
  (void)in_sizes; (void)n_in; (void)out_size; (void)d_ws; (void)ws_size;
  rnn_scan_kernel<<<dim3(RNN_B / 16), dim3(256), 0, stream>>>(x, Wxh, Whh, Why, out);
}